// Round 8
// baseline (1339.123 us; speedup 1.0000x reference)
//
#include <hip/hip_runtime.h>
#include <cstdint>
#include <cstddef>

#define NTOK 8192
#define D    1024
#define DFF  4096
#define NEXP 8
#define CAP  1126
#define MROWS 1280   // 5*256, padded per-expert rows

typedef float f32x4  __attribute__((ext_vector_type(4)));
typedef float f32x16 __attribute__((ext_vector_type(16)));
typedef __bf16 bf16x8 __attribute__((ext_vector_type(8)));

__device__ inline unsigned short f2bf(float f) {
    unsigned u = __float_as_uint(f);
    u += 0x7fffu + ((u >> 16) & 1u);   // round-to-nearest-even
    return (unsigned short)(u >> 16);
}

// fast exact-enough GELU: A&S 7.1.26 erf, |err| <= 1.5e-7 (<< bf16 rounding)
__device__ inline float gelu(float x) {
    float z  = 0.70710678118654752f * x;
    float az = fabsf(z);
    float t  = 1.0f / fmaf(0.3275911f, az, 1.0f);
    float p  = t * fmaf(t, fmaf(t, fmaf(t, fmaf(t, 1.061405429f, -1.453152027f),
                                        1.421413741f), -0.284496736f), 0.254829592f);
    float ee = __expf(-az * az);
    float er = fmaf(-p, ee, 1.0f);
    er = __builtin_copysignf(er, z);
    return 0.5f * x * (1.0f + er);
}

__device__ inline void gload16(const void* g, void* l) {
    __builtin_amdgcn_global_load_lds(
        (const __attribute__((address_space(1))) unsigned int*)g,
        (__attribute__((address_space(3))) unsigned int*)l,
        16, 0, 0);
}

// ---- 128x128 transpose+cvt tile: W[e][K][N] f32 -> WT[e][N][K] bf16 ----
__device__ void transpose_tile_dev(const float* __restrict__ W, unsigned short* __restrict__ WT,
                                   int K, int N, int tb, char* smem)
{
    int tiles_k = K >> 7, tiles_n = N >> 7;
    int per_e = tiles_k * tiles_n;
    int e = tb / per_e, rem = tb % per_e;
    int kb = rem % tiles_k, nb = rem / tiles_k;
    const float* We = W + (size_t)e * K * N + (size_t)(kb * 128) * N + nb * 128;
    unsigned short* Oe = WT + (size_t)e * K * N + (size_t)(nb * 128) * K + kb * 128;
    float* lds = (float*)smem;          // [64][128]
    int t = threadIdx.x;
    #pragma unroll
    for (int p = 0; p < 2; ++p) {
        __syncthreads();
        #pragma unroll
        for (int j = 0; j < 8; ++j) {
            int idx = j * 256 + t;
            int r = idx >> 5, c4 = idx & 31;
            const float4 v = *(const float4*)(We + (size_t)(p * 64 + r) * N + c4 * 4);
            *(float4*)(lds + r * 128 + c4 * 4) = v;
        }
        __syncthreads();
        int c = t >> 1, half = t & 1;
        const float* col = lds + (half * 32) * 128 + c;
        unsigned short* orow = Oe + (size_t)c * K + p * 64 + half * 32;
        #pragma unroll
        for (int q = 0; q < 4; ++q) {
            uint4 o;
            o.x = f2bf(col[(q*8+0)*128]) | ((unsigned)f2bf(col[(q*8+1)*128]) << 16);
            o.y = f2bf(col[(q*8+2)*128]) | ((unsigned)f2bf(col[(q*8+3)*128]) << 16);
            o.z = f2bf(col[(q*8+4)*128]) | ((unsigned)f2bf(col[(q*8+5)*128]) << 16);
            o.w = f2bf(col[(q*8+6)*128]) | ((unsigned)f2bf(col[(q*8+7)*128]) << 16);
            *(uint4*)(orow + q * 8) = o;
        }
    }
}

__global__ __launch_bounds__(256) void transpose_kernel(
    const float* __restrict__ W, unsigned short* __restrict__ WT, int K, int N)
{
    __shared__ __align__(16) char smem[32768];
    transpose_tile_dev(W, WT, K, N, blockIdx.x, smem);
}

// ---------------- router: logits argmax, one wave per token ----------------
__global__ __launch_bounds__(256) void router_kernel(
    const float* __restrict__ x, const float* __restrict__ gw, int* __restrict__ eidx)
{
    int tok  = blockIdx.x * 4 + (threadIdx.x >> 6);
    int lane = threadIdx.x & 63;
    const float* xr = x + (size_t)tok * D;
    float a[8] = {0.f,0.f,0.f,0.f,0.f,0.f,0.f,0.f};
    #pragma unroll
    for (int it = 0; it < D / 64; ++it) {
        int d = lane + it * 64;
        float xv = xr[d];
        const float4 g0 = *(const float4*)(gw + (size_t)d * 8);
        const float4 g1 = *(const float4*)(gw + (size_t)d * 8 + 4);
        a[0] += xv * g0.x; a[1] += xv * g0.y; a[2] += xv * g0.z; a[3] += xv * g0.w;
        a[4] += xv * g1.x; a[5] += xv * g1.y; a[6] += xv * g1.z; a[7] += xv * g1.w;
    }
    #pragma unroll
    for (int off = 32; off > 0; off >>= 1)
        #pragma unroll
        for (int e = 0; e < 8; ++e) a[e] += __shfl_xor(a[e], off, 64);
    if (lane == 0) {
        int bi = 0; float bv = a[0];
        #pragma unroll
        for (int e = 1; e < 8; ++e) if (a[e] > bv) { bv = a[e]; bi = e; }
        eidx[tok] = bi;
    }
}

// ------------- scan: per-expert positions, slot map, drop list, loss -------------
__global__ __launch_bounds__(1024) void scan_kernel(
    const int* __restrict__ eidx, int* __restrict__ slot_map,
    int* __restrict__ kept_cnt, float* __restrict__ loss_out,
    int* __restrict__ droplist, int* __restrict__ dropcnt)
{
    __shared__ int sc[8][1024];
    __shared__ int dcnt;
    int t = threadIdx.x;
    if (t == 0) dcnt = 0;
    int le[8];
    int c[8] = {0,0,0,0,0,0,0,0};
    #pragma unroll
    for (int i = 0; i < 8; ++i) { le[i] = eidx[t * 8 + i]; c[le[i]]++; }
    int v[8];
    #pragma unroll
    for (int e = 0; e < 8; ++e) { v[e] = c[e]; sc[e][t] = v[e]; }
    __syncthreads();
    for (int s = 1; s < 1024; s <<= 1) {
        int add[8] = {0,0,0,0,0,0,0,0};
        if (t >= s) {
            #pragma unroll
            for (int e = 0; e < 8; ++e) add[e] = sc[e][t - s];
        }
        __syncthreads();
        #pragma unroll
        for (int e = 0; e < 8; ++e) { v[e] += add[e]; sc[e][t] = v[e]; }
        __syncthreads();
    }
    int base[8];
    #pragma unroll
    for (int e = 0; e < 8; ++e) base[e] = v[e] - c[e];
    #pragma unroll
    for (int i = 0; i < 8; ++i) {
        int e = le[i]; int pos = base[e]++;
        if (pos < CAP) slot_map[e * CAP + pos] = t * 8 + i;
        else { int s = atomicAdd(&dcnt, 1); droplist[s] = t * 8 + i; }
    }
    __syncthreads();
    if (t == 0) *dropcnt = dcnt;
    if (t == 1023) {
        float dotv = 0.f, ss = 0.f;
        #pragma unroll
        for (int e = 0; e < 8; ++e) {
            float cf = (float)v[e];
            kept_cnt[e] = v[e] < CAP ? v[e] : CAP;
            dotv += cf * 1024.0f;
            ss   += cf * cf;
        }
        float denom = sqrtf(ss) * (1024.0f * sqrtf(8.0f)) + 1e-8f;
        loss_out[0] = 1.0f - 0.01f * (dotv / denom);
    }
}

// ---------------- zero only the dropped token rows ----------------
__global__ __launch_bounds__(256) void zero_dropped(
    const int* __restrict__ droplist, const int* __restrict__ dropcnt,
    float4* __restrict__ out)
{
    int n = (*dropcnt) * 256;            // 256 float4 per row
    for (int idx = blockIdx.x * 256 + threadIdx.x; idx < n; idx += gridDim.x * 256)
        out[(size_t)droplist[idx >> 8] * 256 + (idx & 255)] = make_float4(0.f,0.f,0.f,0.f);
}

// ---------------- dispatch + LayerNorm -> bf16 xbuf [E][MROWS][D] ----------------
__global__ __launch_bounds__(256) void dispatch_ln(
    const float* __restrict__ x, const float* __restrict__ lng, const float* __restrict__ lnb,
    const int* __restrict__ slot_map, const int* __restrict__ kept_cnt,
    unsigned short* __restrict__ xbuf)
{
    int p = blockIdx.x, e = blockIdx.y, tid = threadIdx.x;
    ushort4* dst = (ushort4*)(xbuf + ((size_t)e * MROWS + p) * D) + tid;
    if (p >= kept_cnt[e]) { *dst = make_ushort4(0, 0, 0, 0); return; }
    int tok = slot_map[e * CAP + p];
    const float4 xv = *((const float4*)(x + (size_t)tok * D) + tid);
    float s  = xv.x + xv.y + xv.z + xv.w;
    float ss = xv.x * xv.x + xv.y * xv.y + xv.z * xv.z + xv.w * xv.w;
    #pragma unroll
    for (int off = 32; off > 0; off >>= 1) {
        s  += __shfl_xor(s,  off, 64);
        ss += __shfl_xor(ss, off, 64);
    }
    __shared__ float red[8];
    int lane = tid & 63, wv = tid >> 6;
    if (lane == 0) { red[wv] = s; red[4 + wv] = ss; }
    __syncthreads();
    s  = red[0] + red[1] + red[2] + red[3];
    ss = red[4] + red[5] + red[6] + red[7];
    float mu = s * (1.0f / D);
    float rs = rsqrtf(ss * (1.0f / D) - mu * mu + 1e-5f);
    const float4 gv = *((const float4*)(lng + (size_t)e * D) + tid);
    const float4 bv = *((const float4*)(lnb + (size_t)e * D) + tid);
    ushort4 o;
    o.x = f2bf((xv.x - mu) * rs * gv.x + bv.x);
    o.y = f2bf((xv.y - mu) * rs * gv.y + bv.y);
    o.z = f2bf((xv.z - mu) * rs * gv.z + bv.z);
    o.w = f2bf((xv.w - mu) * rs * gv.w + bv.w);
    *dst = o;
}

// ================= 256x128 GEMM, 32x32x16 MFMA, 4x2 per-wave blocking =================
// C[E][MROWS][N] = A[E][MROWS][K] @ BT[E][N][K]^T + bias
// 256 thr = 4 waves (2Mx2N), per-wave 128x64 = 4x2 of 32x32 tiles, acc 8 x f32x16.
// Fresh LDS bytes per MFMA = 0.375KB (A reused x2, B x4) -- attacks the measured
// 22% operand-BW ceiling.  LDS = 2 bufs x 24KB = 48KB -> 3 blocks/CU: independent
// blocks interleave LDS / MFMA / stage-drain phases (R2/m97 overlap mechanism).
// Hoisted per-thread stage+read offsets (kills the VALU addressing overhead).
// MODE 0: gelu -> bf16 Hout;  MODE 1: fp32 scatter rows (<kept) to Yout.
template<int K, int N, int MODE>
__global__ __launch_bounds__(256, 3) void gemm_kernel(
    const unsigned short* __restrict__ A,
    const unsigned short* __restrict__ BT,
    const float* __restrict__ bias,
    unsigned short* __restrict__ Hout,
    float* __restrict__ Yout,
    const int* __restrict__ slot_map,
    const int* __restrict__ kept_cnt)
{
    constexpr int MB = MROWS / 256;          // 5
    constexpr int NB = N / 128;
    constexpr int GB = NEXP * MB * NB;
    constexpr int T  = K / 32;
    __shared__ __align__(16) char smem[49152];   // 2 x (A 16KB | B 8KB)

    // bijective XCD chunking, mb fastest (B panel shared by 5 consecutive blocks)
    const int obid = blockIdx.x;
    const int q8 = GB >> 3, r8 = GB & 7;
    const int xcd = obid & 7, ii = obid >> 3;
    const int swz = (xcd < r8 ? xcd * (q8 + 1) : r8 * (q8 + 1) + (xcd - r8) * q8) + ii;
    const int mb = swz % MB;
    const int t2 = swz / MB;
    const int nb = t2 % NB;
    const int e  = t2 / NB;

    const int tid  = threadIdx.x;
    const int lane = tid & 63;
    const int l31  = lane & 31, hi = lane >> 5;
    const int wave = tid >> 6;
    const int wr = wave >> 1, wc = wave & 1;     // 2M x 2N
    const unsigned short* Ae = A + ((size_t)e * MROWS + (size_t)mb * 256) * K;
    const unsigned short* Be = BT + ((size_t)e * N + (size_t)nb * 128) * K;

    // hoisted stage source offsets (elements): linear LDS dest, XOR-permuted source
    int srcA[4], srcB[2];
    #pragma unroll
    for (int q = 0; q < 4; ++q) {
        int cid = q * 256 + tid;
        int row = cid >> 2, pp = cid & 3;
        srcA[q] = row * K + (pp ^ ((row >> 1) & 3)) * 8;
    }
    #pragma unroll
    for (int q = 0; q < 2; ++q) {
        int cid = q * 256 + tid;
        int row = cid >> 2, pp = cid & 3;
        srcB[q] = row * K + (pp ^ ((row >> 1) & 3)) * 8;
    }
    // hoisted LDS read byte-offsets (A frags: row=wr*128+m*32+l31, chunk=2ks+hi)
    int offA[4][2], offB[2][2];
    #pragma unroll
    for (int m = 0; m < 4; ++m)
        #pragma unroll
        for (int ks = 0; ks < 2; ++ks) {
            int row = wr * 128 + m * 32 + l31;
            offA[m][ks] = row * 64 + (((2 * ks + hi) ^ ((row >> 1) & 3)) << 4);
        }
    #pragma unroll
    for (int n = 0; n < 2; ++n)
        #pragma unroll
        for (int ks = 0; ks < 2; ++ks) {
            int row = wc * 64 + n * 32 + l31;
            offB[n][ks] = 16384 + row * 64 + (((2 * ks + hi) ^ ((row >> 1) & 3)) << 4);
        }

    f32x16 acc[4][2] = {};

    auto stage = [&](int buf, int kk) {
        char* sb = smem + buf * 24576;
        #pragma unroll
        for (int q = 0; q < 4; ++q)
            gload16(Ae + srcA[q] + kk * 32, sb + (q * 256 + tid) * 16);
        #pragma unroll
        for (int q = 0; q < 2; ++q)
            gload16(Be + srcB[q] + kk * 32, sb + 16384 + (q * 256 + tid) * 16);
    };
    auto compute = [&](int buf) {
        const char* sb = smem + buf * 24576;
        bf16x8 af[4][2], bf[2][2];
        #pragma unroll
        for (int m = 0; m < 4; ++m) {
            af[m][0] = *(const bf16x8*)(sb + offA[m][0]);
            af[m][1] = *(const bf16x8*)(sb + offA[m][1]);
        }
        #pragma unroll
        for (int n = 0; n < 2; ++n) {
            bf[n][0] = *(const bf16x8*)(sb + offB[n][0]);
            bf[n][1] = *(const bf16x8*)(sb + offB[n][1]);
        }
        __builtin_amdgcn_s_setprio(1);
        #pragma unroll
        for (int ks = 0; ks < 2; ++ks)
            #pragma unroll
            for (int m = 0; m < 4; ++m)
                #pragma unroll
                for (int n = 0; n < 2; ++n)
                    acc[m][n] = __builtin_amdgcn_mfma_f32_32x32x16_bf16(
                        bf[n][ks], af[m][ks], acc[m][n], 0, 0, 0);
        __builtin_amdgcn_s_setprio(0);
    };

    stage(0, 0);
    asm volatile("s_waitcnt vmcnt(0)" ::: "memory");
    __syncthreads();
    int cur = 0;
    for (int t = 0; t + 1 < T; ++t) {
        stage(cur ^ 1, t + 1);     // issue next tile; drain overlaps other blocks' compute
        compute(cur);
        asm volatile("s_waitcnt vmcnt(0)" ::: "memory");
        __syncthreads();
        cur ^= 1;
    }
    compute(cur);

    // epilogue: lane owns output row = ...+l31 (per m); reg quad q = 4 consecutive
    // cols at n*32 + q*8 + hi*4 (verified swapped-operand D mapping).
    const int kept = (MODE == 1) ? kept_cnt[e] : 0;
    #pragma unroll
    for (int m = 0; m < 4; ++m) {
        const int row = mb * 256 + wr * 128 + m * 32 + l31;
        int tok = 0; bool live = true;
        if (MODE == 1) {
            live = row < kept;
            tok = live ? slot_map[e * CAP + row] : 0;
        }
        #pragma unroll
        for (int n = 0; n < 2; ++n) {
            #pragma unroll
            for (int q = 0; q < 4; ++q) {
                const int colb = nb * 128 + wc * 64 + n * 32 + q * 8 + hi * 4;
                const float4 bv = *(const float4*)(bias + (size_t)e * N + colb);
                float v0 = acc[m][n][4*q+0] + bv.x;
                float v1 = acc[m][n][4*q+1] + bv.y;
                float v2 = acc[m][n][4*q+2] + bv.z;
                float v3 = acc[m][n][4*q+3] + bv.w;
                if (MODE == 0) {
                    ushort4 o;
                    o.x = f2bf(gelu(v0)); o.y = f2bf(gelu(v1));
                    o.z = f2bf(gelu(v2)); o.w = f2bf(gelu(v3));
                    *(ushort4*)(Hout + ((size_t)e * MROWS + row) * N + colb) = o;
                } else if (live) {
                    *(float4*)(Yout + (size_t)tok * D + colb) = make_float4(v0, v1, v2, v3);
                }
            }
        }
    }
}

extern "C" void kernel_launch(void* const* d_in, const int* in_sizes, int n_in,
                              void* d_out, int out_size, void* d_ws, size_t ws_size,
                              hipStream_t stream)
{
    const float* x   = (const float*)d_in[0];
    const float* gw  = (const float*)d_in[1];
    const float* lng = (const float*)d_in[2];
    const float* lnb = (const float*)d_in[3];
    const float* w1  = (const float*)d_in[4];
    const float* b1  = (const float*)d_in[5];
    const float* w2  = (const float*)d_in[6];
    const float* b2  = (const float*)d_in[7];
    float* out = (float*)d_out;
    char* ws = (char*)d_ws;

    unsigned short* wT   = (unsigned short*)ws;                   // 64MB, reused w1T then w2T
    unsigned short* xbuf = (unsigned short*)(ws + 67108864);      // 8*1280*1024*2 = 20.97MB
    unsigned short* hbuf = (unsigned short*)(ws + 88080384);      // 8*1280*4096*2 = 83.9MB
    int* eidx     = (int*)(ws + 171966464);
    int* slot_map = eidx + NTOK;
    int* kept     = slot_map + NEXP * CAP;
    int* dropcnt  = kept + NEXP;
    int* droplist = dropcnt + 8;   // up to NTOK ints

    constexpr int GB1 = NEXP * (MROWS / 256) * (DFF / 128);   // 1280
    constexpr int GB2 = NEXP * (MROWS / 256) * (D / 128);     // 320
    constexpr int TB1 = NEXP * (D / 128) * (DFF / 128);       // 2048
    constexpr int TB2 = NEXP * (DFF / 128) * (D / 128);       // 2048

    router_kernel<<<NTOK / 4, 256, 0, stream>>>(x, gw, eidx);
    scan_kernel<<<1, 1024, 0, stream>>>(eidx, slot_map, kept,
                                        out + (size_t)NTOK * D, droplist, dropcnt);
    zero_dropped<<<64, 256, 0, stream>>>(droplist, dropcnt, (float4*)out);
    dispatch_ln<<<dim3(MROWS, NEXP), 256, 0, stream>>>(x, lng, lnb, slot_map, kept, xbuf);

    transpose_kernel<<<TB1, 256, 0, stream>>>(w1, wT, D, DFF);
    gemm_kernel<D, DFF, 0><<<GB1, 256, 0, stream>>>(
        xbuf, wT, b1, hbuf, nullptr, slot_map, kept);

    transpose_kernel<<<TB2, 256, 0, stream>>>(w2, wT, DFF, D);
    gemm_kernel<DFF, D, 1><<<GB2, 256, 0, stream>>>(
        hbuf, wT, b2, nullptr, out, slot_map, kept);
}

// Round 9
// 342.440 us; speedup vs baseline: 3.9105x; 3.9105x over previous
//
#include <hip/hip_runtime.h>
#include <cstdint>
#include <cstddef>

#define NTOK 8192
#define D    1024
#define DFF  4096
#define NEXP 8
#define CAP  1126
#define MPAD 1152   // 9*128, padded per-expert rows

typedef float f32x4 __attribute__((ext_vector_type(4)));
typedef __bf16 bf16x8 __attribute__((ext_vector_type(8)));

__device__ inline unsigned short f2bf(float f) {
    unsigned u = __float_as_uint(f);
    u += 0x7fffu + ((u >> 16) & 1u);   // round-to-nearest-even
    return (unsigned short)(u >> 16);
}

// fast exact-enough GELU: A&S 7.1.26 erf, |err| <= 1.5e-7 (<< bf16 rounding)
__device__ inline float gelu(float x) {
    float z  = 0.70710678118654752f * x;
    float az = fabsf(z);
    float t  = 1.0f / fmaf(0.3275911f, az, 1.0f);
    float p  = t * fmaf(t, fmaf(t, fmaf(t, fmaf(t, 1.061405429f, -1.453152027f),
                                        1.421413741f), -0.284496736f), 0.254829592f);
    float ee = __expf(-az * az);
    float er = fmaf(-p, ee, 1.0f);
    er = __builtin_copysignf(er, z);
    return 0.5f * x * (1.0f + er);
}

__device__ inline void gload16(const void* g, void* l) {
    __builtin_amdgcn_global_load_lds(
        (const __attribute__((address_space(1))) unsigned int*)g,
        (__attribute__((address_space(3))) unsigned int*)l,
        16, 0, 0);
}

// ---- 128x128 transpose+cvt tile: W[e][K][N] f32 -> WT[e][N][K] bf16 ----
__global__ __launch_bounds__(256) void transpose_kernel(
    const float* __restrict__ W, unsigned short* __restrict__ WT, int K, int N)
{
    __shared__ __align__(16) char smem[32768];
    int tb = blockIdx.x;
    int tiles_k = K >> 7, tiles_n = N >> 7;
    int per_e = tiles_k * tiles_n;
    int e = tb / per_e, rem = tb % per_e;
    int kb = rem % tiles_k, nb = rem / tiles_k;
    const float* We = W + (size_t)e * K * N + (size_t)(kb * 128) * N + nb * 128;
    unsigned short* Oe = WT + (size_t)e * K * N + (size_t)(nb * 128) * K + kb * 128;
    float* lds = (float*)smem;          // [64][128]
    int t = threadIdx.x;
    #pragma unroll
    for (int p = 0; p < 2; ++p) {
        __syncthreads();
        #pragma unroll
        for (int j = 0; j < 8; ++j) {
            int idx = j * 256 + t;
            int r = idx >> 5, c4 = idx & 31;
            const float4 v = *(const float4*)(We + (size_t)(p * 64 + r) * N + c4 * 4);
            *(float4*)(lds + r * 128 + c4 * 4) = v;
        }
        __syncthreads();
        int c = t >> 1, half = t & 1;
        const float* col = lds + (half * 32) * 128 + c;
        unsigned short* orow = Oe + (size_t)c * K + p * 64 + half * 32;
        #pragma unroll
        for (int q = 0; q < 4; ++q) {
            uint4 o;
            o.x = f2bf(col[(q*8+0)*128]) | ((unsigned)f2bf(col[(q*8+1)*128]) << 16);
            o.y = f2bf(col[(q*8+2)*128]) | ((unsigned)f2bf(col[(q*8+3)*128]) << 16);
            o.z = f2bf(col[(q*8+4)*128]) | ((unsigned)f2bf(col[(q*8+5)*128]) << 16);
            o.w = f2bf(col[(q*8+6)*128]) | ((unsigned)f2bf(col[(q*8+7)*128]) << 16);
            *(uint4*)(orow + q * 8) = o;
        }
    }
}

// ---------------- router: logits argmax, one wave per token ----------------
__global__ __launch_bounds__(256) void router_kernel(
    const float* __restrict__ x, const float* __restrict__ gw, int* __restrict__ eidx)
{
    int tok  = blockIdx.x * 4 + (threadIdx.x >> 6);
    int lane = threadIdx.x & 63;
    const float* xr = x + (size_t)tok * D;
    float a[8] = {0.f,0.f,0.f,0.f,0.f,0.f,0.f,0.f};
    #pragma unroll
    for (int it = 0; it < D / 64; ++it) {
        int d = lane + it * 64;
        float xv = xr[d];
        const float4 g0 = *(const float4*)(gw + (size_t)d * 8);
        const float4 g1 = *(const float4*)(gw + (size_t)d * 8 + 4);
        a[0] += xv * g0.x; a[1] += xv * g0.y; a[2] += xv * g0.z; a[3] += xv * g0.w;
        a[4] += xv * g1.x; a[5] += xv * g1.y; a[6] += xv * g1.z; a[7] += xv * g1.w;
    }
    #pragma unroll
    for (int off = 32; off > 0; off >>= 1)
        #pragma unroll
        for (int e = 0; e < 8; ++e) a[e] += __shfl_xor(a[e], off, 64);
    if (lane == 0) {
        int bi = 0; float bv = a[0];
        #pragma unroll
        for (int e = 1; e < 8; ++e) if (a[e] > bv) { bv = a[e]; bi = e; }
        eidx[tok] = bi;
    }
}

// ------------- scan: per-expert positions, slot map, drop list, loss -------------
__global__ __launch_bounds__(1024) void scan_kernel(
    const int* __restrict__ eidx, int* __restrict__ slot_map,
    int* __restrict__ kept_cnt, float* __restrict__ loss_out,
    int* __restrict__ droplist, int* __restrict__ dropcnt)
{
    __shared__ int sc[8][1024];
    __shared__ int dcnt;
    int t = threadIdx.x;
    if (t == 0) dcnt = 0;
    int le[8];
    int c[8] = {0,0,0,0,0,0,0,0};
    #pragma unroll
    for (int i = 0; i < 8; ++i) { le[i] = eidx[t * 8 + i]; c[le[i]]++; }
    int v[8];
    #pragma unroll
    for (int e = 0; e < 8; ++e) { v[e] = c[e]; sc[e][t] = v[e]; }
    __syncthreads();
    for (int s = 1; s < 1024; s <<= 1) {
        int add[8] = {0,0,0,0,0,0,0,0};
        if (t >= s) {
            #pragma unroll
            for (int e = 0; e < 8; ++e) add[e] = sc[e][t - s];
        }
        __syncthreads();
        #pragma unroll
        for (int e = 0; e < 8; ++e) { v[e] += add[e]; sc[e][t] = v[e]; }
        __syncthreads();
    }
    int base[8];
    #pragma unroll
    for (int e = 0; e < 8; ++e) base[e] = v[e] - c[e];
    #pragma unroll
    for (int i = 0; i < 8; ++i) {
        int e = le[i]; int pos = base[e]++;
        if (pos < CAP) slot_map[e * CAP + pos] = t * 8 + i;
        else { int s = atomicAdd(&dcnt, 1); droplist[s] = t * 8 + i; }
    }
    __syncthreads();
    if (t == 0) *dropcnt = dcnt;
    if (t == 1023) {
        float dotv = 0.f, ss = 0.f;
        #pragma unroll
        for (int e = 0; e < 8; ++e) {
            float cf = (float)v[e];
            kept_cnt[e] = v[e] < CAP ? v[e] : CAP;
            dotv += cf * 1024.0f;
            ss   += cf * cf;
        }
        float denom = sqrtf(ss) * (1024.0f * sqrtf(8.0f)) + 1e-8f;
        loss_out[0] = 1.0f - 0.01f * (dotv / denom);
    }
}

// ---------------- zero only the dropped token rows ----------------
__global__ __launch_bounds__(256) void zero_dropped(
    const int* __restrict__ droplist, const int* __restrict__ dropcnt,
    float4* __restrict__ out)
{
    int n = (*dropcnt) * 256;            // 256 float4 per row
    for (int idx = blockIdx.x * 256 + threadIdx.x; idx < n; idx += gridDim.x * 256)
        out[(size_t)droplist[idx >> 8] * 256 + (idx & 255)] = make_float4(0.f,0.f,0.f,0.f);
}

// ---------------- dispatch + LayerNorm -> bf16 xbuf [E][MPAD][D] ----------------
__global__ __launch_bounds__(256) void dispatch_ln(
    const float* __restrict__ x, const float* __restrict__ lng, const float* __restrict__ lnb,
    const int* __restrict__ slot_map, const int* __restrict__ kept_cnt,
    unsigned short* __restrict__ xbuf)
{
    int p = blockIdx.x, e = blockIdx.y, tid = threadIdx.x;
    ushort4* dst = (ushort4*)(xbuf + ((size_t)e * MPAD + p) * D) + tid;
    if (p >= kept_cnt[e]) { *dst = make_ushort4(0, 0, 0, 0); return; }
    int tok = slot_map[e * CAP + p];
    const float4 xv = *((const float4*)(x + (size_t)tok * D) + tid);
    float s  = xv.x + xv.y + xv.z + xv.w;
    float ss = xv.x * xv.x + xv.y * xv.y + xv.z * xv.z + xv.w * xv.w;
    #pragma unroll
    for (int off = 32; off > 0; off >>= 1) {
        s  += __shfl_xor(s,  off, 64);
        ss += __shfl_xor(ss, off, 64);
    }
    __shared__ float red[8];
    int lane = tid & 63, wv = tid >> 6;
    if (lane == 0) { red[wv] = s; red[4 + wv] = ss; }
    __syncthreads();
    s  = red[0] + red[1] + red[2] + red[3];
    ss = red[4] + red[5] + red[6] + red[7];
    float mu = s * (1.0f / D);
    float rs = rsqrtf(ss * (1.0f / D) - mu * mu + 1e-5f);
    const float4 gv = *((const float4*)(lng + (size_t)e * D) + tid);
    const float4 bv = *((const float4*)(lnb + (size_t)e * D) + tid);
    ushort4 o;
    o.x = f2bf((xv.x - mu) * rs * gv.x + bv.x);
    o.y = f2bf((xv.y - mu) * rs * gv.y + bv.y);
    o.z = f2bf((xv.z - mu) * rs * gv.z + bv.z);
    o.w = f2bf((xv.w - mu) * rs * gv.w + bv.w);
    *dst = o;
}

// ---------------- GEMM: C[E][MPAD][N] = A[E][MPAD][K] @ BT[E][N][K]^T + bias ----------------
// 128x128 tile, BK=32.  3-buffer LDS pipeline, prefetch distance 2, counted
// vmcnt(4) (never 0 mid-loop).  Disjointness per iter t: read buf[t%3], issue
// writes to buf[(t+2)%3], in-flight writes target buf[(t+1)%3]; lgkmcnt(0)
// before the barrier keeps slow waves' ds_reads ahead of the next overwrite.
// 48KB LDS x 3 blocks/CU = 144KB: cross-block overlap hides residual latency.
// Swapped MFMA operands -> thread owns 4 consecutive output cols (vector epilogue).
// MODE 0: gelu -> bf16 Hout;  MODE 1: fp32 scatter rows (<kept) to Yout.
template<int K, int N, int MODE>
__global__ __launch_bounds__(256, 3) void gemm_kernel(
    const unsigned short* __restrict__ A,
    const unsigned short* __restrict__ BT,
    const float* __restrict__ bias,
    unsigned short* __restrict__ Hout,
    float* __restrict__ Yout,
    const int* __restrict__ slot_map,
    const int* __restrict__ kept_cnt)
{
    constexpr int MB = MPAD / 128;
    constexpr int NB = N / 128;
    constexpr int GB = NEXP * MB * NB;
    constexpr int T  = K / 32;
    __shared__ __align__(16) char smem[49152];   // 3 x (A 8KB | B 8KB)

    // bijective XCD chunking, mb fastest (one XCD's 9 consecutive blocks share a B panel)
    const int obid = blockIdx.x;
    const int q8 = GB >> 3, r8 = GB & 7;
    const int xcd = obid & 7, ii = obid >> 3;
    const int swz = (xcd < r8 ? xcd * (q8 + 1) : r8 * (q8 + 1) + (xcd - r8) * q8) + ii;
    const int mb = swz % MB;
    const int t2 = swz / MB;
    const int nb = t2 % NB;
    const int e  = t2 / NB;

    const int tid  = threadIdx.x;
    const int lane = tid & 63;
    const int l15  = lane & 15, lg = lane >> 4;
    const int wave = tid >> 6, wr = wave >> 1, wc = wave & 1;
    const unsigned short* Ae = A + ((size_t)e * MPAD + (size_t)mb * 128) * K;
    const unsigned short* Be = BT + ((size_t)e * N + (size_t)nb * 128) * K;
    f32x4 acc[4][4] = {};

    auto stage = [&](int buf, int kk) {
        char* sA = smem + buf * 16384;
        char* sB = sA + 8192;
        #pragma unroll
        for (int q = 0; q < 2; ++q) {
            int cid = q * 256 + tid;          // 0..511 chunk of 16B
            int row = cid >> 2, pp = cid & 3;
            int cc  = pp ^ ((row >> 1) & 3);  // source chunk for swizzled LDS pos
            gload16(Ae + (size_t)row * K + kk * 32 + cc * 8, sA + cid * 16);
            gload16(Be + (size_t)row * K + kk * 32 + cc * 8, sB + cid * 16);
        }
    };
    auto compute = [&](int buf) {
        const char* sA = smem + buf * 16384;
        const char* sB = sA + 8192;
        bf16x8 af[4], bfr[4];
        #pragma unroll
        for (int i = 0; i < 4; ++i) {
            int ra = wr * 64 + i * 16 + l15;
            af[i]  = *(const bf16x8*)(sA + ra * 64 + ((lg ^ ((ra >> 1) & 3)) << 4));
            int rb = wc * 64 + i * 16 + l15;
            bfr[i] = *(const bf16x8*)(sB + rb * 64 + ((lg ^ ((rb >> 1) & 3)) << 4));
        }
        __builtin_amdgcn_s_setprio(1);
        #pragma unroll
        for (int mi = 0; mi < 4; ++mi)
            #pragma unroll
            for (int ni = 0; ni < 4; ++ni)
                acc[mi][ni] = __builtin_amdgcn_mfma_f32_16x16x32_bf16(
                    bfr[ni], af[mi], acc[mi][ni], 0, 0, 0);   // swapped: thread owns 4 cols
        __builtin_amdgcn_s_setprio(0);
    };

    // prologue: tiles 0,1 in flight; wait only for tile 0 (4 loads/stage)
    stage(0, 0);
    stage(1, 1);
    asm volatile("s_waitcnt vmcnt(4)" ::: "memory");
    __builtin_amdgcn_s_barrier();
    asm volatile("" ::: "memory");
    int b = 0;
    for (int t = 0; t < T - 2; ++t) {
        int bn = b + 2; if (bn >= 3) bn -= 3;
        stage(bn, t + 2);                 // issue tile t+2 (waited 2 iters from now)
        compute(b);                       // compute tile t
        asm volatile("s_waitcnt vmcnt(4) lgkmcnt(0)" ::: "memory");  // tile t+1 ready
        __builtin_amdgcn_s_barrier();
        asm volatile("" ::: "memory");
        b = (b == 2) ? 0 : b + 1;
    }
    compute(b);                           // tile T-2
    asm volatile("s_waitcnt vmcnt(0) lgkmcnt(0)" ::: "memory");
    __builtin_amdgcn_s_barrier();
    asm volatile("" ::: "memory");
    b = (b == 2) ? 0 : b + 1;
    compute(b);                           // tile T-1

    // epilogue: row = ...+l15 (per mi), 4 consecutive cols = ...+4*lg (per ni)
    const int kept = (MODE == 1) ? kept_cnt[e] : 0;
    #pragma unroll
    for (int mi = 0; mi < 4; ++mi) {
        const int row = mb * 128 + wr * 64 + mi * 16 + l15;
        int tok = 0; bool live = true;
        if (MODE == 1) {
            live = row < kept;
            tok = live ? slot_map[e * CAP + row] : 0;
        }
        #pragma unroll
        for (int ni = 0; ni < 4; ++ni) {
            const int colb = nb * 128 + wc * 64 + ni * 16 + 4 * lg;
            const float4 bv = *(const float4*)(bias + (size_t)e * N + colb);
            if (MODE == 0) {
                ushort4 o;
                o.x = f2bf(gelu(acc[mi][ni][0] + bv.x));
                o.y = f2bf(gelu(acc[mi][ni][1] + bv.y));
                o.z = f2bf(gelu(acc[mi][ni][2] + bv.z));
                o.w = f2bf(gelu(acc[mi][ni][3] + bv.w));
                *(ushort4*)(Hout + ((size_t)e * MPAD + row) * N + colb) = o;
            } else if (live) {
                float4 o = make_float4(acc[mi][ni][0] + bv.x, acc[mi][ni][1] + bv.y,
                                       acc[mi][ni][2] + bv.z, acc[mi][ni][3] + bv.w);
                *(float4*)(Yout + (size_t)tok * D + colb) = o;
            }
        }
    }
}

extern "C" void kernel_launch(void* const* d_in, const int* in_sizes, int n_in,
                              void* d_out, int out_size, void* d_ws, size_t ws_size,
                              hipStream_t stream)
{
    const float* x   = (const float*)d_in[0];
    const float* gw  = (const float*)d_in[1];
    const float* lng = (const float*)d_in[2];
    const float* lnb = (const float*)d_in[3];
    const float* w1  = (const float*)d_in[4];
    const float* b1  = (const float*)d_in[5];
    const float* w2  = (const float*)d_in[6];
    const float* b2  = (const float*)d_in[7];
    float* out = (float*)d_out;
    char* ws = (char*)d_ws;

    unsigned short* wT   = (unsigned short*)ws;                          // 64MB, reused w1T then w2T
    unsigned short* xbuf = (unsigned short*)(ws + 67108864);             // 18.9MB
    unsigned short* hbuf = (unsigned short*)(ws + 67108864 + 18874368);  // 75.5MB
    int* eidx     = (int*)(ws + 161480704);
    int* slot_map = eidx + NTOK;
    int* kept     = slot_map + NEXP * CAP;
    int* dropcnt  = kept + NEXP;
    int* droplist = dropcnt + 8;   // up to NTOK ints

    constexpr int GB1 = NEXP * (MPAD / 128) * (DFF / 128);   // 2304
    constexpr int GB2 = NEXP * (MPAD / 128) * (D / 128);     // 576
    constexpr int TB  = 2048;                                // 128x128 transpose tiles per weight

    router_kernel<<<NTOK / 4, 256, 0, stream>>>(x, gw, eidx);
    scan_kernel<<<1, 1024, 0, stream>>>(eidx, slot_map, kept,
                                        out + (size_t)NTOK * D, droplist, dropcnt);
    zero_dropped<<<64, 256, 0, stream>>>(droplist, dropcnt, (float4*)out);
    dispatch_ln<<<dim3(MPAD, NEXP), 256, 0, stream>>>(x, lng, lnb, slot_map, kept, xbuf);

    transpose_kernel<<<TB, 256, 0, stream>>>(w1, wT, D, DFF);
    gemm_kernel<D, DFF, 0><<<GB1, 256, 0, stream>>>(
        xbuf, wT, b1, hbuf, nullptr, slot_map, kept);

    transpose_kernel<<<TB, 256, 0, stream>>>(w2, wT, DFF, D);
    gemm_kernel<DFF, D, 1><<<GB2, 256, 0, stream>>>(
        hbuf, wT, b2, nullptr, out, slot_map, kept);
}

// Round 10
// 341.274 us; speedup vs baseline: 3.9239x; 1.0034x over previous
//
#include <hip/hip_runtime.h>
#include <cstdint>
#include <cstddef>

#define NTOK 8192
#define D    1024
#define DFF  4096
#define NEXP 8
#define CAP  1126
#define MPAD 1152   // 9*128, padded per-expert rows

typedef float f32x4 __attribute__((ext_vector_type(4)));
typedef __bf16 bf16x8 __attribute__((ext_vector_type(8)));

__device__ inline unsigned short f2bf(float f) {
    unsigned u = __float_as_uint(f);
    u += 0x7fffu + ((u >> 16) & 1u);   // round-to-nearest-even
    return (unsigned short)(u >> 16);
}

// fast exact-enough GELU: A&S 7.1.26 erf, |err| <= 1.5e-7 (<< bf16 rounding)
__device__ inline float gelu(float x) {
    float z  = 0.70710678118654752f * x;
    float az = fabsf(z);
    float t  = 1.0f / fmaf(0.3275911f, az, 1.0f);
    float p  = t * fmaf(t, fmaf(t, fmaf(t, fmaf(t, 1.061405429f, -1.453152027f),
                                        1.421413741f), -0.284496736f), 0.254829592f);
    float ee = __expf(-az * az);
    float er = fmaf(-p, ee, 1.0f);
    er = __builtin_copysignf(er, z);
    return 0.5f * x * (1.0f + er);
}

__device__ inline void gload16(const void* g, void* l) {
    __builtin_amdgcn_global_load_lds(
        (const __attribute__((address_space(1))) unsigned int*)g,
        (__attribute__((address_space(3))) unsigned int*)l,
        16, 0, 0);
}

// ---- 128x128 transpose+cvt tile: W[e][K][N] f32 -> WT[e][N][K] bf16 (32KB LDS) ----
__device__ void transpose_tile_dev(const float* __restrict__ W, unsigned short* __restrict__ WT,
                                   int K, int N, int tb, char* smem)
{
    int tiles_k = K >> 7, tiles_n = N >> 7;
    int per_e = tiles_k * tiles_n;
    int e = tb / per_e, rem = tb % per_e;
    int kb = rem % tiles_k, nb = rem / tiles_k;
    const float* We = W + (size_t)e * K * N + (size_t)(kb * 128) * N + nb * 128;
    unsigned short* Oe = WT + (size_t)e * K * N + (size_t)(nb * 128) * K + kb * 128;
    float* lds = (float*)smem;          // [64][128]
    int t = threadIdx.x;
    #pragma unroll
    for (int p = 0; p < 2; ++p) {
        __syncthreads();
        #pragma unroll
        for (int j = 0; j < 8; ++j) {
            int idx = j * 256 + t;
            int r = idx >> 5, c4 = idx & 31;
            const float4 v = *(const float4*)(We + (size_t)(p * 64 + r) * N + c4 * 4);
            *(float4*)(lds + r * 128 + c4 * 4) = v;
        }
        __syncthreads();
        int c = t >> 1, half = t & 1;
        const float* col = lds + (half * 32) * 128 + c;
        unsigned short* orow = Oe + (size_t)c * K + p * 64 + half * 32;
        #pragma unroll
        for (int q = 0; q < 4; ++q) {
            uint4 o;
            o.x = f2bf(col[(q*8+0)*128]) | ((unsigned)f2bf(col[(q*8+1)*128]) << 16);
            o.y = f2bf(col[(q*8+2)*128]) | ((unsigned)f2bf(col[(q*8+3)*128]) << 16);
            o.z = f2bf(col[(q*8+4)*128]) | ((unsigned)f2bf(col[(q*8+5)*128]) << 16);
            o.w = f2bf(col[(q*8+6)*128]) | ((unsigned)f2bf(col[(q*8+7)*128]) << 16);
            *(uint4*)(orow + q * 8) = o;
        }
    }
}

// ---------------- router: logits argmax, one wave per token ----------------
__global__ __launch_bounds__(256) void router_kernel(
    const float* __restrict__ x, const float* __restrict__ gw, int* __restrict__ eidx)
{
    int tok  = blockIdx.x * 4 + (threadIdx.x >> 6);
    int lane = threadIdx.x & 63;
    const float* xr = x + (size_t)tok * D;
    float a[8] = {0.f,0.f,0.f,0.f,0.f,0.f,0.f,0.f};
    #pragma unroll
    for (int it = 0; it < D / 64; ++it) {
        int d = lane + it * 64;
        float xv = xr[d];
        const float4 g0 = *(const float4*)(gw + (size_t)d * 8);
        const float4 g1 = *(const float4*)(gw + (size_t)d * 8 + 4);
        a[0] += xv * g0.x; a[1] += xv * g0.y; a[2] += xv * g0.z; a[3] += xv * g0.w;
        a[4] += xv * g1.x; a[5] += xv * g1.y; a[6] += xv * g1.z; a[7] += xv * g1.w;
    }
    #pragma unroll
    for (int off = 32; off > 0; off >>= 1)
        #pragma unroll
        for (int e = 0; e < 8; ++e) a[e] += __shfl_xor(a[e], off, 64);
    if (lane == 0) {
        int bi = 0; float bv = a[0];
        #pragma unroll
        for (int e = 1; e < 8; ++e) if (a[e] > bv) { bv = a[e]; bi = e; }
        eidx[tok] = bi;
    }
}

// ------ fused: block 0 = 256-thread scan (slot map, drops, loss); blocks 1.. = w1 transpose ------
__global__ __launch_bounds__(256) void fused_scan_trA(
    const int* __restrict__ eidx, int* __restrict__ slot_map,
    int* __restrict__ kept_cnt, float* __restrict__ loss_out,
    int* __restrict__ droplist, int* __restrict__ dropcnt,
    const float* __restrict__ W1, unsigned short* __restrict__ WT1)
{
    __shared__ __align__(16) char smem[32768];
    if (blockIdx.x > 0) {
        transpose_tile_dev(W1, WT1, D, DFF, blockIdx.x - 1, smem);
        return;
    }
    // ---- scan over 8192 tokens, 32 per thread ----
    int (*sc)[256] = (int(*)[256])smem;          // [8][256] = 8KB
    __shared__ int dcnt;
    int t = threadIdx.x;
    if (t == 0) dcnt = 0;
    int le[32];
    int c[8] = {0,0,0,0,0,0,0,0};
    #pragma unroll
    for (int i = 0; i < 32; ++i) { le[i] = eidx[t * 32 + i]; c[le[i]]++; }
    int v[8];
    #pragma unroll
    for (int e = 0; e < 8; ++e) { v[e] = c[e]; sc[e][t] = v[e]; }
    __syncthreads();
    for (int s = 1; s < 256; s <<= 1) {
        int add[8] = {0,0,0,0,0,0,0,0};
        if (t >= s) {
            #pragma unroll
            for (int e = 0; e < 8; ++e) add[e] = sc[e][t - s];
        }
        __syncthreads();
        #pragma unroll
        for (int e = 0; e < 8; ++e) { v[e] += add[e]; sc[e][t] = v[e]; }
        __syncthreads();
    }
    int base[8];
    #pragma unroll
    for (int e = 0; e < 8; ++e) base[e] = v[e] - c[e];
    #pragma unroll
    for (int i = 0; i < 32; ++i) {
        int e = le[i]; int pos = base[e]++;
        if (pos < CAP) slot_map[e * CAP + pos] = t * 32 + i;
        else { int s = atomicAdd(&dcnt, 1); droplist[s] = t * 32 + i; }
    }
    __syncthreads();
    if (t == 0) *dropcnt = dcnt;
    if (t == 255) {
        float dotv = 0.f, ss = 0.f;
        #pragma unroll
        for (int e = 0; e < 8; ++e) {
            float cf = (float)v[e];
            kept_cnt[e] = v[e] < CAP ? v[e] : CAP;
            dotv += cf * 1024.0f;
            ss   += cf * cf;
        }
        float denom = sqrtf(ss) * (1024.0f * sqrtf(8.0f)) + 1e-8f;
        loss_out[0] = 1.0f - 0.01f * (dotv / denom);
    }
}

// ------ fused: blocks 0..2047 w2 transpose; 2048..2111 zero dropped rows; rest dispatch+LN ------
#define TRB 2048
#define ZB  64
__global__ __launch_bounds__(256) void fused_disp_trB(
    const float* __restrict__ x, const float* __restrict__ lng, const float* __restrict__ lnb,
    const int* __restrict__ slot_map, const int* __restrict__ kept_cnt,
    unsigned short* __restrict__ xbuf,
    const int* __restrict__ droplist, const int* __restrict__ dropcnt,
    float4* __restrict__ out,
    const float* __restrict__ W2, unsigned short* __restrict__ WT2)
{
    __shared__ __align__(16) char smem[32768];
    const int bid = blockIdx.x;
    if (bid < TRB) {                       // long pole first: w2 transpose
        transpose_tile_dev(W2, WT2, DFF, D, bid, smem);
        return;
    }
    if (bid < TRB + ZB) {                  // zero dropped token rows
        int n = (*dropcnt) * 256;          // 256 float4 per row
        for (int idx = (bid - TRB) * 256 + threadIdx.x; idx < n; idx += ZB * 256)
            out[(size_t)droplist[idx >> 8] * 256 + (idx & 255)] = make_float4(0.f,0.f,0.f,0.f);
        return;
    }
    // ---- dispatch + LayerNorm ----
    int rem = bid - TRB - ZB;
    int p = rem % MPAD, e = rem / MPAD, tid = threadIdx.x;
    ushort4* dst = (ushort4*)(xbuf + ((size_t)e * MPAD + p) * D) + tid;
    if (p >= kept_cnt[e]) { *dst = make_ushort4(0, 0, 0, 0); return; }
    int tok = slot_map[e * CAP + p];
    const float4 xv = *((const float4*)(x + (size_t)tok * D) + tid);
    float s  = xv.x + xv.y + xv.z + xv.w;
    float ss = xv.x * xv.x + xv.y * xv.y + xv.z * xv.z + xv.w * xv.w;
    #pragma unroll
    for (int off = 32; off > 0; off >>= 1) {
        s  += __shfl_xor(s,  off, 64);
        ss += __shfl_xor(ss, off, 64);
    }
    float* red = (float*)smem;
    int lane = tid & 63, wv = tid >> 6;
    if (lane == 0) { red[wv] = s; red[4 + wv] = ss; }
    __syncthreads();
    s  = red[0] + red[1] + red[2] + red[3];
    ss = red[4] + red[5] + red[6] + red[7];
    float mu = s * (1.0f / D);
    float rs = rsqrtf(ss * (1.0f / D) - mu * mu + 1e-5f);
    const float4 gv = *((const float4*)(lng + (size_t)e * D) + tid);
    const float4 bv = *((const float4*)(lnb + (size_t)e * D) + tid);
    ushort4 o;
    o.x = f2bf((xv.x - mu) * rs * gv.x + bv.x);
    o.y = f2bf((xv.y - mu) * rs * gv.y + bv.y);
    o.z = f2bf((xv.z - mu) * rs * gv.z + bv.z);
    o.w = f2bf((xv.w - mu) * rs * gv.w + bv.w);
    *dst = o;
}

// ---------------- GEMM: identical to R9 (proven best) ----------------
// 128x128 tile, BK=32.  3-buffer LDS pipeline, prefetch distance 2, counted
// vmcnt(4).  48KB x 3 blocks/CU; swapped MFMA operands -> vector epilogue.
// MODE 0: gelu -> bf16 Hout;  MODE 1: fp32 scatter rows (<kept) to Yout.
template<int K, int N, int MODE>
__global__ __launch_bounds__(256, 3) void gemm_kernel(
    const unsigned short* __restrict__ A,
    const unsigned short* __restrict__ BT,
    const float* __restrict__ bias,
    unsigned short* __restrict__ Hout,
    float* __restrict__ Yout,
    const int* __restrict__ slot_map,
    const int* __restrict__ kept_cnt)
{
    constexpr int MB = MPAD / 128;
    constexpr int NB = N / 128;
    constexpr int GB = NEXP * MB * NB;
    constexpr int T  = K / 32;
    __shared__ __align__(16) char smem[49152];   // 3 x (A 8KB | B 8KB)

    const int obid = blockIdx.x;
    const int q8 = GB >> 3, r8 = GB & 7;
    const int xcd = obid & 7, ii = obid >> 3;
    const int swz = (xcd < r8 ? xcd * (q8 + 1) : r8 * (q8 + 1) + (xcd - r8) * q8) + ii;
    const int mb = swz % MB;
    const int t2 = swz / MB;
    const int nb = t2 % NB;
    const int e  = t2 / NB;

    const int tid  = threadIdx.x;
    const int lane = tid & 63;
    const int l15  = lane & 15, lg = lane >> 4;
    const int wave = tid >> 6, wr = wave >> 1, wc = wave & 1;
    const unsigned short* Ae = A + ((size_t)e * MPAD + (size_t)mb * 128) * K;
    const unsigned short* Be = BT + ((size_t)e * N + (size_t)nb * 128) * K;
    f32x4 acc[4][4] = {};

    auto stage = [&](int buf, int kk) {
        char* sA = smem + buf * 16384;
        char* sB = sA + 8192;
        #pragma unroll
        for (int q = 0; q < 2; ++q) {
            int cid = q * 256 + tid;
            int row = cid >> 2, pp = cid & 3;
            int cc  = pp ^ ((row >> 1) & 3);
            gload16(Ae + (size_t)row * K + kk * 32 + cc * 8, sA + cid * 16);
            gload16(Be + (size_t)row * K + kk * 32 + cc * 8, sB + cid * 16);
        }
    };
    auto compute = [&](int buf) {
        const char* sA = smem + buf * 16384;
        const char* sB = sA + 8192;
        bf16x8 af[4], bfr[4];
        #pragma unroll
        for (int i = 0; i < 4; ++i) {
            int ra = wr * 64 + i * 16 + l15;
            af[i]  = *(const bf16x8*)(sA + ra * 64 + ((lg ^ ((ra >> 1) & 3)) << 4));
            int rb = wc * 64 + i * 16 + l15;
            bfr[i] = *(const bf16x8*)(sB + rb * 64 + ((lg ^ ((rb >> 1) & 3)) << 4));
        }
        __builtin_amdgcn_s_setprio(1);
        #pragma unroll
        for (int mi = 0; mi < 4; ++mi)
            #pragma unroll
            for (int ni = 0; ni < 4; ++ni)
                acc[mi][ni] = __builtin_amdgcn_mfma_f32_16x16x32_bf16(
                    bfr[ni], af[mi], acc[mi][ni], 0, 0, 0);
        __builtin_amdgcn_s_setprio(0);
    };

    stage(0, 0);
    stage(1, 1);
    asm volatile("s_waitcnt vmcnt(4)" ::: "memory");
    __builtin_amdgcn_s_barrier();
    asm volatile("" ::: "memory");
    int b = 0;
    for (int t = 0; t < T - 2; ++t) {
        int bn = b + 2; if (bn >= 3) bn -= 3;
        stage(bn, t + 2);
        compute(b);
        asm volatile("s_waitcnt vmcnt(4) lgkmcnt(0)" ::: "memory");
        __builtin_amdgcn_s_barrier();
        asm volatile("" ::: "memory");
        b = (b == 2) ? 0 : b + 1;
    }
    compute(b);
    asm volatile("s_waitcnt vmcnt(0) lgkmcnt(0)" ::: "memory");
    __builtin_amdgcn_s_barrier();
    asm volatile("" ::: "memory");
    b = (b == 2) ? 0 : b + 1;
    compute(b);

    const int kept = (MODE == 1) ? kept_cnt[e] : 0;
    #pragma unroll
    for (int mi = 0; mi < 4; ++mi) {
        const int row = mb * 128 + wr * 64 + mi * 16 + l15;
        int tok = 0; bool live = true;
        if (MODE == 1) {
            live = row < kept;
            tok = live ? slot_map[e * CAP + row] : 0;
        }
        #pragma unroll
        for (int ni = 0; ni < 4; ++ni) {
            const int colb = nb * 128 + wc * 64 + ni * 16 + 4 * lg;
            const float4 bv = *(const float4*)(bias + (size_t)e * N + colb);
            if (MODE == 0) {
                ushort4 o;
                o.x = f2bf(gelu(acc[mi][ni][0] + bv.x));
                o.y = f2bf(gelu(acc[mi][ni][1] + bv.y));
                o.z = f2bf(gelu(acc[mi][ni][2] + bv.z));
                o.w = f2bf(gelu(acc[mi][ni][3] + bv.w));
                *(ushort4*)(Hout + ((size_t)e * MPAD + row) * N + colb) = o;
            } else if (live) {
                float4 o = make_float4(acc[mi][ni][0] + bv.x, acc[mi][ni][1] + bv.y,
                                       acc[mi][ni][2] + bv.z, acc[mi][ni][3] + bv.w);
                *(float4*)(Yout + (size_t)tok * D + colb) = o;
            }
        }
    }
}

extern "C" void kernel_launch(void* const* d_in, const int* in_sizes, int n_in,
                              void* d_out, int out_size, void* d_ws, size_t ws_size,
                              hipStream_t stream)
{
    const float* x   = (const float*)d_in[0];
    const float* gw  = (const float*)d_in[1];
    const float* lng = (const float*)d_in[2];
    const float* lnb = (const float*)d_in[3];
    const float* w1  = (const float*)d_in[4];
    const float* b1  = (const float*)d_in[5];
    const float* w2  = (const float*)d_in[6];
    const float* b2  = (const float*)d_in[7];
    float* out = (float*)d_out;
    char* ws = (char*)d_ws;

    // ws >= 228626432 (proven by R4's fuse-path pass)
    unsigned short* wT1  = (unsigned short*)ws;                    // [0,64MB)
    unsigned short* wT2  = (unsigned short*)(ws + 67108864);       // [64,128MB)
    unsigned short* xbuf = (unsigned short*)(ws + 134217728);      // 18.9MB
    unsigned short* hbuf = (unsigned short*)(ws + 153092096);      // 75.5MB
    int* slot_map = (int*)(ws + 228589568);                        // 36032B
    int* kept     = slot_map + NEXP * CAP;
    int* dropcnt  = kept + NEXP;
    // eidx / droplist alias the hbuf prefix (dead until GEMM1 writes hbuf)
    int* eidx     = (int*)hbuf;
    int* droplist = (int*)hbuf + NTOK;

    constexpr int GB1 = NEXP * (MPAD / 128) * (DFF / 128);   // 2304
    constexpr int GB2 = NEXP * (MPAD / 128) * (D / 128);     // 576

    router_kernel<<<NTOK / 4, 256, 0, stream>>>(x, gw, eidx);
    fused_scan_trA<<<1 + 2048, 256, 0, stream>>>(
        eidx, slot_map, kept, out + (size_t)NTOK * D, droplist, dropcnt, w1, wT1);
    fused_disp_trB<<<TRB + ZB + MPAD * NEXP, 256, 0, stream>>>(
        x, lng, lnb, slot_map, kept, xbuf, droplist, dropcnt, (float4*)out, w2, wT2);
    gemm_kernel<D, DFF, 0><<<GB1, 256, 0, stream>>>(
        xbuf, wT1, b1, hbuf, nullptr, slot_map, kept);
    gemm_kernel<DFF, D, 1><<<GB2, 256, 0, stream>>>(
        hbuf, wT2, b2, nullptr, out, slot_map, kept);
}